// Round 1
// baseline (205.166 us; speedup 1.0000x reference)
//
#include <hip/hip_runtime.h>
#include <math.h>

#define NPIX 4096

// ---------------------------------------------------------------------------
// Kernel 1: fused QKV 1x1-conv GEMM. out[o,p] = sum_c W[o,c] x[c,p]
// grid (32 p-tiles, 8 o-tiles(=heads), 3 mats), 256 threads.
// Epilogue: q,k -> sigmoid; v -> per-(head,pixel) L2 normalize (o-tile == head).
// ---------------------------------------------------------------------------
__global__ __launch_bounds__(256) void qkv_kernel(
    const float* __restrict__ x, const float* __restrict__ Wq,
    const float* __restrict__ Wk, const float* __restrict__ Wv,
    float* __restrict__ qo, float* __restrict__ ko, float* __restrict__ vo)
{
    const int pt = blockIdx.x * 128;
    const int ot = blockIdx.y * 32;
    const int mat = blockIdx.z;
    const float* __restrict__ W = (mat == 0) ? Wq : ((mat == 1) ? Wk : Wv);
    float* __restrict__ out = (mat == 0) ? qo : ((mat == 1) ? ko : vo);

    __shared__ float Xs[32][132];   // stride 132 floats = 528 B (16B-aligned rows)
    __shared__ float Ws[32][33];

    const int t = threadIdx.x;
    const int pc = t & 31;   // pixel group (4 consecutive px)
    const int oc = t >> 5;   // output group (4 outputs)

    float acc[4][4];
#pragma unroll
    for (int j = 0; j < 4; j++)
#pragma unroll
        for (int i = 0; i < 4; i++) acc[j][i] = 0.f;

    for (int kt = 0; kt < 256; kt += 32) {
#pragma unroll
        for (int i = 0; i < 4; i++) {
            int idx = t + (i << 8);            // 0..1023 float4 slots
            int c = idx >> 5;
            int p4 = (idx & 31) << 2;
            float4 val = *reinterpret_cast<const float4*>(x + (kt + c) * NPIX + pt + p4);
            *reinterpret_cast<float4*>(&Xs[c][p4]) = val;
        }
#pragma unroll
        for (int i = 0; i < 4; i++) {
            int idx = t + (i << 8);
            int o = idx >> 5;
            int c = idx & 31;
            Ws[o][c] = W[(ot + o) * 256 + kt + c];
        }
        __syncthreads();
#pragma unroll
        for (int kk = 0; kk < 32; kk++) {
            float4 a = *reinterpret_cast<const float4*>(&Xs[kk][pc << 2]);
            float av[4] = {a.x, a.y, a.z, a.w};
            float bv[4];
#pragma unroll
            for (int j = 0; j < 4; j++) bv[j] = Ws[(oc << 2) + j][kk];
#pragma unroll
            for (int j = 0; j < 4; j++)
#pragma unroll
                for (int i = 0; i < 4; i++)
                    acc[j][i] = fmaf(bv[j], av[i], acc[j][i]);
        }
        __syncthreads();
    }

    if (mat < 2) {
        // sigmoid epilogue
#pragma unroll
        for (int j = 0; j < 4; j++) {
            const int o = ot + (oc << 2) + j;
            float4 r;
            r.x = 1.f / (1.f + __expf(-acc[j][0]));
            r.y = 1.f / (1.f + __expf(-acc[j][1]));
            r.z = 1.f / (1.f + __expf(-acc[j][2]));
            r.w = 1.f / (1.f + __expf(-acc[j][3]));
            *reinterpret_cast<float4*>(out + o * NPIX + pt + (pc << 2)) = r;
        }
    } else {
        // v: L2-normalize over the 32 channels of this head (== this o-tile)
        float* scratch = &Ws[0][0];   // 1056 floats available, need 1024
#pragma unroll
        for (int i = 0; i < 4; i++) {
            float ss = 0.f;
#pragma unroll
            for (int j = 0; j < 4; j++) ss += acc[j][i] * acc[j][i];
            scratch[oc * 128 + (pc << 2) + i] = ss;
        }
        __syncthreads();
        float scale[4];
#pragma unroll
        for (int i = 0; i < 4; i++) {
            float tot = 0.f;
#pragma unroll
            for (int g = 0; g < 8; g++) tot += scratch[g * 128 + (pc << 2) + i];
            scale[i] = 1.f / fmaxf(sqrtf(tot), 1e-12f);
        }
#pragma unroll
        for (int j = 0; j < 4; j++) {
            const int o = ot + (oc << 2) + j;
            float4 r;
            r.x = acc[j][0] * scale[0];
            r.y = acc[j][1] * scale[1];
            r.z = acc[j][2] * scale[2];
            r.w = acc[j][3] * scale[3];
            *reinterpret_cast<float4*>(out + o * NPIX + pt + (pc << 2)) = r;
        }
    }
}

// ---------------------------------------------------------------------------
// Kernel 2: per-(head, f) fused integral-image + windowed contraction.
// For each d in [0,32): build P = zero-padded 2D prefix sum of k[d]*v[f] in
// LDS, then acc[w][px] += q[d,px] * boxdiff(P, window w).
// f == 32 is the norm slot (v == 1), writing nrm = 1/(acc + 1e-6).
// grid (33, 8, S); 256 threads.
// ---------------------------------------------------------------------------
template <int S>
__global__ __launch_bounds__(256) void attn_kernel(
    const float* __restrict__ q, const float* __restrict__ k,
    const float* __restrict__ v, float* __restrict__ num, float* __restrict__ nrm)
{
    const int f = blockIdx.x;
    const int head = blockIdx.y;
    const int s = blockIdx.z;
    const bool isnorm = (f == 32);

    const float* __restrict__ kh = k + head * 32 * NPIX;
    const float* __restrict__ qh = q + head * 32 * NPIX;
    const float* __restrict__ vf = v + (head * 32 + (isnorm ? 0 : f)) * NPIX;

    __shared__ float prod[64][65];
    __shared__ float P[65][67];     // stride 67 -> odd bank walk, conflict-free
    __shared__ float psum[64][5];

    const int t = threadIdx.x;
    const int lane64 = t & 63;
    const int seg = t >> 6;

    if (t <= 64) { P[t][0] = 0.f; P[0][t] = 0.f; }

    float vreg[16];
#pragma unroll
    for (int i = 0; i < 16; i++) vreg[i] = isnorm ? 1.f : vf[t + (i << 8)];

    constexpr int PPT = 16 / S;
    float acc[3][PPT];
#pragma unroll
    for (int w = 0; w < 3; w++)
#pragma unroll
        for (int i = 0; i < PPT; i++) acc[w][i] = 0.f;

    __syncthreads();

    for (int d = 0; d < 32; d++) {
        // phase 1: products into LDS
        const float* __restrict__ kd = kh + d * NPIX;
#pragma unroll
        for (int i = 0; i < 16; i++) {
            int pp = t + (i << 8);
            prod[pp >> 6][pp & 63] = kd[pp] * vreg[i];
        }
        __syncthreads();
        // phase 2: row prefix scan (4 segments of 16 per row)
        {
            float r[16];
            float run = 0.f;
            const int x0 = seg << 4;
#pragma unroll
            for (int j = 0; j < 16; j++) { run += prod[lane64][x0 + j]; r[j] = run; }
            psum[lane64][seg] = run;
            __syncthreads();
            float off = 0.f;
#pragma unroll
            for (int sg = 0; sg < 3; sg++) if (sg < seg) off += psum[lane64][sg];
#pragma unroll
            for (int j = 0; j < 16; j++) P[lane64 + 1][x0 + 1 + j] = r[j] + off;
            __syncthreads();
        }
        // phase 3: column prefix scan in place on P rows 1..64
        {
            float r[16];
            float run = 0.f;
            const int y0 = (seg << 4) + 1;
            const int c = lane64 + 1;
#pragma unroll
            for (int j = 0; j < 16; j++) { run += P[y0 + j][c]; r[j] = run; }
            psum[lane64][seg] = run;
            __syncthreads();
            float off = 0.f;
#pragma unroll
            for (int sg = 0; sg < 3; sg++) if (sg < seg) off += psum[lane64][sg];
#pragma unroll
            for (int j = 0; j < 16; j++) P[y0 + j][c] = r[j] + off;
            __syncthreads();
        }
        // phase 4: windowed box-diff contraction with q[d]
        const float* __restrict__ qd = qh + d * NPIX;
#pragma unroll
        for (int i = 0; i < PPT; i++) {
            const int pp = s * (NPIX / S) + (i << 8) + t;
            const float qv = qd[pp];
            const int y = pp >> 6;
            const int x = pp & 63;
#pragma unroll
            for (int w = 0; w < 3; w++) {
                const int hw = 32 >> w;                       // half-widths 32,16,8
                const int ylo = max(y - hw, 0), yhi = min(y + hw, 64);
                const int xlo = max(x - hw, 0), xhi = min(x + hw, 64);
                const float wkv = P[yhi][xhi] - P[yhi][xlo] - P[ylo][xhi] + P[ylo][xlo];
                acc[w][i] = fmaf(qv, wkv, acc[w][i]);
            }
        }
        __syncthreads();   // protect P before next iteration's scans
    }

#pragma unroll
    for (int w = 0; w < 3; w++) {
#pragma unroll
        for (int i = 0; i < PPT; i++) {
            const int pp = s * (NPIX / S) + (i << 8) + t;
            if (isnorm) {
                nrm[(w * 8 + head) * NPIX + pp] = 1.f / (acc[w][i] + 1e-6f);
            } else {
                num[((w * 8 + head) * 32 + f) * NPIX + pp] = acc[w][i];
            }
        }
    }
}

// ---------------------------------------------------------------------------
// Kernel 3: final 1x1 conv. out[o,p] = bout[o] + sum_{w,ch} Wout[o, w*256+ch]
//            * num[w,ch,p] * nrm[w,ch/32,p]   (nrm pre-reciprocated)
// grid (32 p-tiles, 8 o-tiles), 256 threads, K = 768 in 24 tiles of 32
// (each K-tile is exactly one (w, head) pair).
// ---------------------------------------------------------------------------
__global__ __launch_bounds__(256) void out_kernel(
    const float* __restrict__ num, const float* __restrict__ nrm,
    const float* __restrict__ Wout, const float* __restrict__ bout,
    float* __restrict__ out)
{
    const int pt = blockIdx.x * 128;
    const int ot = blockIdx.y * 32;
    __shared__ float As[32][132];
    __shared__ float Ws[32][33];
    const int t = threadIdx.x;
    const int pc = t & 31;
    const int oc = t >> 5;

    float acc[4][4];
#pragma unroll
    for (int j = 0; j < 4; j++)
#pragma unroll
        for (int i = 0; i < 4; i++) acc[j][i] = 0.f;

    for (int kt = 0; kt < 24; kt++) {
        const int w = kt >> 3;
        const int head = kt & 7;
        const float* __restrict__ numt = num + (size_t)(w * 8 + head) * 32 * NPIX;
        const float* __restrict__ nt = nrm + (w * 8 + head) * NPIX;
#pragma unroll
        for (int i = 0; i < 4; i++) {
            int idx = t + (i << 8);
            int c = idx >> 5;
            int p4 = (idx & 31) << 2;
            float4 nv = *reinterpret_cast<const float4*>(numt + c * NPIX + pt + p4);
            float4 rv = *reinterpret_cast<const float4*>(nt + pt + p4);
            nv.x *= rv.x; nv.y *= rv.y; nv.z *= rv.z; nv.w *= rv.w;
            *reinterpret_cast<float4*>(&As[c][p4]) = nv;
        }
#pragma unroll
        for (int i = 0; i < 4; i++) {
            int idx = t + (i << 8);
            int o = idx >> 5;
            int c = idx & 31;
            Ws[o][c] = Wout[(ot + o) * 768 + kt * 32 + c];
        }
        __syncthreads();
#pragma unroll
        for (int kk = 0; kk < 32; kk++) {
            float4 a = *reinterpret_cast<const float4*>(&As[kk][pc << 2]);
            float av[4] = {a.x, a.y, a.z, a.w};
            float bv[4];
#pragma unroll
            for (int j = 0; j < 4; j++) bv[j] = Ws[(oc << 2) + j][kk];
#pragma unroll
            for (int j = 0; j < 4; j++)
#pragma unroll
                for (int i = 0; i < 4; i++)
                    acc[j][i] = fmaf(bv[j], av[i], acc[j][i]);
        }
        __syncthreads();
    }

#pragma unroll
    for (int j = 0; j < 4; j++) {
        const int o = ot + (oc << 2) + j;
        const float bb = bout[o];
        float4 r;
        r.x = acc[j][0] + bb;
        r.y = acc[j][1] + bb;
        r.z = acc[j][2] + bb;
        r.w = acc[j][3] + bb;
        *reinterpret_cast<float4*>(out + o * NPIX + pt + (pc << 2)) = r;
    }
}

extern "C" void kernel_launch(void* const* d_in, const int* in_sizes, int n_in,
                              void* d_out, int out_size, void* d_ws, size_t ws_size,
                              hipStream_t stream)
{
    const float* x    = (const float*)d_in[0];
    const float* Wq   = (const float*)d_in[1];
    const float* Wk   = (const float*)d_in[2];
    const float* Wv   = (const float*)d_in[3];
    const float* Wout = (const float*)d_in[4];
    const float* bout = (const float*)d_in[5];
    float* out = (float*)d_out;

    float* ws  = (float*)d_ws;
    float* q   = ws;                  // 1,048,576 floats
    float* k   = q + 1048576;         // 1,048,576
    float* v   = k + 1048576;         // 1,048,576
    float* num = v + 1048576;         // 3,145,728
    float* nrm = num + 3145728;       // 98,304   (stored as reciprocal)

    qkv_kernel<<<dim3(32, 8, 3), 256, 0, stream>>>(x, Wq, Wk, Wv, q, k, v);
    attn_kernel<2><<<dim3(33, 8, 2), 256, 0, stream>>>(q, k, v, num, nrm);
    out_kernel<<<dim3(32, 8), 256, 0, stream>>>(num, nrm, Wout, bout, out);
}